// Round 10
// baseline (2355.211 us; speedup 1.0000x reference)
//
#include <hip/hip_runtime.h>
#include <math.h>

#define NLOC 4096
#define NREP 128
#define MN   48
#define XTS  141   // xs_t row stride (odd -> conflict-free gather writes)
#define WLS  141   // wl row stride

// Bank swizzle: shift each 32-dword block by 4 dwords so the 16 8-dword
// chunks read by a wave's tj lanes cover all 32 banks (<=2-way, free on
// CDNA4). Chunks never cross a 32-block boundary, float4 stays contiguous.
__device__ __forceinline__ int swz(int j) { return j + ((j >> 5) << 2); }

__device__ __forceinline__ float bcast(float v, int lane) {
    return __builtin_bit_cast(float,
        __builtin_amdgcn_readlane(__builtin_bit_cast(int, v), lane));
}

// One block per location. 256 threads as a 16x16 grid of 8x8 register tiles:
// thread (ti,tj) owns rows 8*ti..8*ti+7, cols 8*tj..8*tj+7 of the FULL 128x128
// matrix (symmetric maintenance -> Cholesky pivot column == pivot row).
//
// Blocked right-looking Cholesky, 8-wide panels:
//   - panel p factored in-wave: pivot broadcasts via v_readlane + v_rcp/v_rsq
//     (the 128-step serial pivot chain is the block's critical path);
//   - normalized panel rows published to double-buffered LDS, ONE
//     __syncthreads per panel (16 total);
//   - trailing rank-8 update fully in registers, no runtime masks.
// acc[][] is never runtime-indexed (scratch-demotion hazard).
//
// LDS: xs_t (Gram phase) and wl (Cholesky phase) are never live at the same
// time -- aliased in one buffer. 28.7 KB => LDS cap = 5 blocks/CU.
//
// launch_bounds NOTE: observed across R1/R3/R6 that resident blocks/CU ~=
// the 2nd launch_bounds arg (2->1.9, 3->2.8, 3->2.8) even with LDS/VGPR
// headroom -- the waves-per-eu attr behaves as an occupancy SETPOINT on
// this toolchain. Requesting 5 (the LDS cap). VGPR budget at 5 waves/EU
// = 102 >= the 84 this kernel needs, so the R2 spill mode is excluded.
__global__ __launch_bounds__(256, 5)
void otm_fused(const float* __restrict__ aug,
               const float* __restrict__ theta,
               const float* __restrict__ scales,
               const float* __restrict__ nug_mean,
               const int*   __restrict__ batch_idx,
               float* __restrict__ out_g,
               float* __restrict__ out_l)
{
    __shared__ float smem_buf[MN * XTS];   // 27072 B: xs_t, then wl (aliased)
    __shared__ float ldiag[NREP];
    __shared__ float scal_s[MN];
    __shared__ float rs_s[NREP];           // 1/sqrt(c_kk) per column

    float* xs_t = smem_buf;                          // [MN][XTS]
    typedef float wl_row[WLS];
    typedef wl_row wl_panel[8];
    wl_panel* wl = (wl_panel*)smem_buf;              // wl[2][8][WLS], 9024 B

    const int loc = blockIdx.x;
    const int tid = threadIdx.x;
    const int ti  = tid >> 4;
    const int tj  = tid & 15;
    const int i0  = ti << 3;   // first owned row
    const int j0  = tj << 3;   // first owned col
    const int sa  = swz(i0);   // swizzled LDS offset of row block
    const int sb  = swz(j0);   // swizzled LDS offset of col block

    // --- per-k feature scaling: scal[k] = sqrt(exp(-(k+1)*exp(theta2))) ---
    const float th2 = theta[2];
    if (tid < MN) {
        float e2 = expf(th2);
        scal_s[tid] = expf(-0.5f * (float)(tid + 1) * e2);
    }
    __syncthreads();

    // --- gather aug[:,loc,1:49], NaN->0, scale, into LDS (transposed) ---
    for (int idx = tid; idx < NREP * MN; idx += 256) {
        int r = idx / MN;          // rep 0..127
        int c = idx - r * MN;      // feature 0..47
        float v = aug[(r * NLOC + loc) * (MN + 1) + 1 + c];
        v = (v != v) ? 0.0f : v;
        xs_t[c * XTS + swz(r)] = v * scal_s[c];
    }
    __syncthreads();

    // --- row norms (diagonal of Gram), threads 0..127 ---
    if (tid < NREP) {
        const int sr = swz(tid);
        float s = 0.0f;
        #pragma unroll
        for (int kk = 0; kk < MN; ++kk) {
            float v = xs_t[kk * XTS + sr];
            s = fmaf(v, v, s);
        }
        ldiag[tid] = s;
    }

    // --- Gram: acc[r][c] = sum_k xs[i0+r][k]*xs[j0+c][k] (vector LDS reads) ---
    float acc[8][8];
    #pragma unroll
    for (int r = 0; r < 8; ++r)
        #pragma unroll
        for (int c = 0; c < 8; ++c) acc[r][c] = 0.0f;

    #pragma unroll 4
    for (int kk = 0; kk < MN; ++kk) {
        const float* row = &xs_t[kk * XTS];
        const float4 aA = *(const float4*)(row + sa);
        const float4 aB = *(const float4*)(row + sa + 4);
        const float4 bA = *(const float4*)(row + sb);
        const float4 bB = *(const float4*)(row + sb + 4);
        const float a[8] = {aA.x, aA.y, aA.z, aA.w, aB.x, aB.y, aB.z, aB.w};
        const float b[8] = {bA.x, bA.y, bA.z, bA.w, bB.x, bB.y, bB.z, bB.w};
        #pragma unroll
        for (int r = 0; r < 8; ++r)
            #pragma unroll
            for (int c = 0; c < 8; ++c)
                acc[r][c] = fmaf(a[r], b[c], acc[r][c]);
    }
    __syncthreads();   // ldiag ready; ALL xs_t reads retired (wl may now alias)

    // --- elementwise transform: G = (lin + sig2*matern)/nug + I ---
    const float s_loc   = scales[loc];
    const float th3 = theta[3], th4 = theta[4], th5 = theta[5];
    const float sig2    = expf(2.0f * fmaf(logf(s_loc), th4, th3));
    const float nug_inv = 1.0f / nug_mean[loc];
    const float ls      = expf(th5) * 1.7320508075688772f;  // sqrt(2*1.5)
    const float inv_ls2 = 1.0f / (ls * ls);
    const bool  is0     = (batch_idx[loc] == 0);

    float di[8], dj[8];
    #pragma unroll
    for (int r = 0; r < 8; ++r) di[r] = ldiag[i0 + r];
    #pragma unroll
    for (int c = 0; c < 8; ++c) dj[c] = ldiag[j0 + c];

    float* gout = out_g + (size_t)loc * (NREP * NREP);
    #pragma unroll
    for (int r = 0; r < 8; ++r) {
        const int i = i0 + r;
        #pragma unroll
        for (int h = 0; h < 2; ++h) {
            float tmp[4];
            #pragma unroll
            for (int e = 0; e < 4; ++e) {
                const int c = h * 4 + e;
                const int j = j0 + c;
                float lin = acc[r][c];
                float sq  = (di[r] + dj[c] - 2.0f * lin) * inv_ls2;
                sq = fmaxf(sq, 0.0f);
                float d3  = 1.7320508075688772f * __builtin_amdgcn_sqrtf(sq);
                float mat = (1.0f + d3) * __expf(-d3);
                float gv  = fmaf(sig2, mat, lin) * nug_inv + ((i == j) ? 1.0f : 0.0f);
                if (is0) gv = (i == j) ? 1.0f : 0.0f;
                acc[r][c] = gv;
                tmp[e] = gv;
            }
            *(float4*)(gout + (size_t)i * NREP + j0 + h * 4) =
                make_float4(tmp[0], tmp[1], tmp[2], tmp[3]);
        }
    }

    // --- blocked Cholesky. Invariant: unnormalized c_ij = L_ij * L_jj. ---
    for (int p = 0; p < 16; ++p) {
        // in-wave panel factorization: threads (ti==p, tj>=p), lanes
        // (p%4)*16+tj of wave p/4; diag tile lives on lane (p%4)*16+p.
        if (ti == p && tj >= p) {
            const int diagLane = ((p & 3) << 4) | p;
            float rsv[8];
            #pragma unroll
            for (int s = 0; s < 8; ++s) {
                const float piv  = bcast(acc[s][s], diagLane);
                const float dinv = __builtin_amdgcn_rcpf(piv);
                rsv[s] = __builtin_amdgcn_rsqf(piv);
                #pragma unroll
                for (int sp = s + 1; sp < 8; ++sp) {
                    const float f = bcast(acc[sp][s], diagLane) * dinv;
                    #pragma unroll
                    for (int c = 0; c < 8; ++c) {
                        if (c > s) {                     // compile-time mask (diag tile)
                            acc[sp][c] = fmaf(-f, acc[s][c], acc[sp][c]);
                        } else if (tj > p) {             // cols right of panel: full
                            acc[sp][c] = fmaf(-f, acc[s][c], acc[sp][c]);
                        }
                    }
                }
            }
            // publish normalized panel rows: wl[s][j] = c_{k,j}/sqrt(c_kk) = L_{j,k}
            #pragma unroll
            for (int s = 0; s < 8; ++s) {
                *(float4*)&wl[p & 1][s][sb] =
                    make_float4(acc[s][0] * rsv[s], acc[s][1] * rsv[s],
                                acc[s][2] * rsv[s], acc[s][3] * rsv[s]);
                *(float4*)&wl[p & 1][s][sb + 4] =
                    make_float4(acc[s][4] * rsv[s], acc[s][5] * rsv[s],
                                acc[s][6] * rsv[s], acc[s][7] * rsv[s]);
            }
            if (tj == p) {
                #pragma unroll
                for (int s = 0; s < 8; ++s) rs_s[(p << 3) + s] = rsv[s];
            }
        }
        __syncthreads();   // the ONLY barrier per panel

        // trailing rank-8 update: rows below the panel only (ti>p).
        if (ti > p) {
            const wl_row* w = wl[p & 1];
            if (tj > p) {
                // full 8x8x8, no masks
                #pragma unroll 2
                for (int s = 0; s < 8; ++s) {
                    const float4 wiA = *(const float4*)&w[s][sa];
                    const float4 wiB = *(const float4*)&w[s][sa + 4];
                    const float4 wjA = *(const float4*)&w[s][sb];
                    const float4 wjB = *(const float4*)&w[s][sb + 4];
                    const float wi[8] = {wiA.x, wiA.y, wiA.z, wiA.w,
                                         wiB.x, wiB.y, wiB.z, wiB.w};
                    const float wj[8] = {wjA.x, wjA.y, wjA.z, wjA.w,
                                         wjB.x, wjB.y, wjB.z, wjB.w};
                    #pragma unroll
                    for (int r = 0; r < 8; ++r)
                        #pragma unroll
                        for (int c = 0; c < 8; ++c)
                            acc[r][c] = fmaf(-wi[r], wj[c], acc[r][c]);
                }
            } else if (tj == p) {
                // panel columns below the diag block: only k < j terms (s < c),
                // all masks compile-time.
                #pragma unroll
                for (int s = 0; s < 7; ++s) {
                    const float4 wiA = *(const float4*)&w[s][sa];
                    const float4 wiB = *(const float4*)&w[s][sa + 4];
                    const float wi[8] = {wiA.x, wiA.y, wiA.z, wiA.w,
                                         wiB.x, wiB.y, wiB.z, wiB.w};
                    #pragma unroll
                    for (int c = 0; c < 8; ++c) {
                        if (c > s) {
                            const float wjc = w[s][sb + c];
                            #pragma unroll
                            for (int r = 0; r < 8; ++r)
                                acc[r][c] = fmaf(-wi[r], wjc, acc[r][c]);
                        }
                    }
                }
            }
        }
    }

    // --- epilogue: L[i][j] = c_ij / sqrt(c_jj), zeros above diagonal ---
    float rsj[8];
    #pragma unroll
    for (int c = 0; c < 8; ++c) rsj[c] = rs_s[j0 + c];

    float* lout = out_l + (size_t)loc * (NREP * NREP);
    #pragma unroll
    for (int r = 0; r < 8; ++r) {
        const int i = i0 + r;
        #pragma unroll
        for (int h = 0; h < 2; ++h) {
            float tmp[4];
            #pragma unroll
            for (int e = 0; e < 4; ++e) {
                const int c = h * 4 + e;
                const int j = j0 + c;
                tmp[e] = (i >= j) ? acc[r][c] * rsj[c] : 0.0f;
            }
            *(float4*)(lout + (size_t)i * NREP + j0 + h * 4) =
                make_float4(tmp[0], tmp[1], tmp[2], tmp[3]);
        }
    }
}

extern "C" void kernel_launch(void* const* d_in, const int* in_sizes, int n_in,
                              void* d_out, int out_size, void* d_ws, size_t ws_size,
                              hipStream_t stream) {
    const float* aug    = (const float*)d_in[0];
    const float* theta  = (const float*)d_in[1];
    const float* scales = (const float*)d_in[2];
    const float* nug    = (const float*)d_in[3];
    const int*   bidx   = (const int*)d_in[4];
    float* g = (float*)d_out;
    float* l = g + (size_t)NLOC * NREP * NREP;
    hipLaunchKernelGGL(otm_fused, dim3(NLOC), dim3(256), 0, stream,
                       aug, theta, scales, nug, bidx, g, l);
}

// Round 11
// 1437.804 us; speedup vs baseline: 1.6381x; 1.6381x over previous
//
#include <hip/hip_runtime.h>
#include <math.h>

#define NLOC 4096
#define NREP 128
#define MN   48
#define XTS  141   // xs_t row stride (odd -> conflict-free gather writes)
#define WLS  141   // wl row stride

// ============================ DIAGNOSTIC ROUND ============================
// R10 post-mortem: VGPR budget ~= 256/launch_bounds_arg (2->128,3->84,4->64,
// 5->48); bound>3 spills acc[8][8] (R10: 2GB/3.1GB scratch, 1950us). Bound 3
// is the constrained optimum. Occupancy lever dead; per-phase wall share
// unknown (model underpredicts dur 3x). THIS ROUND: run the Cholesky
// trailing-update exactly TWICE (wl published scaled by 1/sqrt2, two
// half-rank updates == one full update up to ulp rounding; tol 0.25 >> this).
// delta(dur) vs 718us = trailing update's wall share. Directs next rounds.
// ==========================================================================

// Bank swizzle: shift each 32-dword block by 4 dwords so the 16 8-dword
// chunks read by a wave's tj lanes cover all 32 banks (<=2-way, free on
// CDNA4). Chunks never cross a 32-block boundary, float4 stays contiguous.
__device__ __forceinline__ int swz(int j) { return j + ((j >> 5) << 2); }

__device__ __forceinline__ float bcast(float v, int lane) {
    return __builtin_bit_cast(float,
        __builtin_amdgcn_readlane(__builtin_bit_cast(int, v), lane));
}

__global__ __launch_bounds__(256, 3)
void otm_fused(const float* __restrict__ aug,
               const float* __restrict__ theta,
               const float* __restrict__ scales,
               const float* __restrict__ nug_mean,
               const int*   __restrict__ batch_idx,
               float* __restrict__ out_g,
               float* __restrict__ out_l)
{
    __shared__ float smem_buf[MN * XTS];   // 27072 B: xs_t, then wl (aliased)
    __shared__ float ldiag[NREP];
    __shared__ float scal_s[MN];
    __shared__ float rs_s[NREP];           // 1/sqrt(c_kk) per column

    float* xs_t = smem_buf;                          // [MN][XTS]
    typedef float wl_row[WLS];
    typedef wl_row wl_panel[8];
    wl_panel* wl = (wl_panel*)smem_buf;              // wl[2][8][WLS], 9024 B

    const int loc = blockIdx.x;
    const int tid = threadIdx.x;
    const int ti  = tid >> 4;
    const int tj  = tid & 15;
    const int i0  = ti << 3;   // first owned row
    const int j0  = tj << 3;   // first owned col
    const int sa  = swz(i0);   // swizzled LDS offset of row block
    const int sb  = swz(j0);   // swizzled LDS offset of col block

    // --- per-k feature scaling: scal[k] = sqrt(exp(-(k+1)*exp(theta2))) ---
    const float th2 = theta[2];
    if (tid < MN) {
        float e2 = expf(th2);
        scal_s[tid] = expf(-0.5f * (float)(tid + 1) * e2);
    }
    __syncthreads();

    // --- gather aug[:,loc,1:49], NaN->0, scale, into LDS (transposed) ---
    for (int idx = tid; idx < NREP * MN; idx += 256) {
        int r = idx / MN;          // rep 0..127
        int c = idx - r * MN;      // feature 0..47
        float v = aug[(r * NLOC + loc) * (MN + 1) + 1 + c];
        v = (v != v) ? 0.0f : v;
        xs_t[c * XTS + swz(r)] = v * scal_s[c];
    }
    __syncthreads();

    // --- row norms (diagonal of Gram), threads 0..127 ---
    if (tid < NREP) {
        const int sr = swz(tid);
        float s = 0.0f;
        #pragma unroll
        for (int kk = 0; kk < MN; ++kk) {
            float v = xs_t[kk * XTS + sr];
            s = fmaf(v, v, s);
        }
        ldiag[tid] = s;
    }

    // --- Gram: acc[r][c] = sum_k xs[i0+r][k]*xs[j0+c][k] (vector LDS reads) ---
    float acc[8][8];
    #pragma unroll
    for (int r = 0; r < 8; ++r)
        #pragma unroll
        for (int c = 0; c < 8; ++c) acc[r][c] = 0.0f;

    #pragma unroll 4
    for (int kk = 0; kk < MN; ++kk) {
        const float* row = &xs_t[kk * XTS];
        const float4 aA = *(const float4*)(row + sa);
        const float4 aB = *(const float4*)(row + sa + 4);
        const float4 bA = *(const float4*)(row + sb);
        const float4 bB = *(const float4*)(row + sb + 4);
        const float a[8] = {aA.x, aA.y, aA.z, aA.w, aB.x, aB.y, aB.z, aB.w};
        const float b[8] = {bA.x, bA.y, bA.z, bA.w, bB.x, bB.y, bB.z, bB.w};
        #pragma unroll
        for (int r = 0; r < 8; ++r)
            #pragma unroll
            for (int c = 0; c < 8; ++c)
                acc[r][c] = fmaf(a[r], b[c], acc[r][c]);
    }
    __syncthreads();   // ldiag ready; ALL xs_t reads retired (wl may now alias)

    // --- elementwise transform: G = (lin + sig2*matern)/nug + I ---
    const float s_loc   = scales[loc];
    const float th3 = theta[3], th4 = theta[4], th5 = theta[5];
    const float sig2    = expf(2.0f * fmaf(logf(s_loc), th4, th3));
    const float nug_inv = 1.0f / nug_mean[loc];
    const float ls      = expf(th5) * 1.7320508075688772f;  // sqrt(2*1.5)
    const float inv_ls2 = 1.0f / (ls * ls);
    const bool  is0     = (batch_idx[loc] == 0);

    float di[8], dj[8];
    #pragma unroll
    for (int r = 0; r < 8; ++r) di[r] = ldiag[i0 + r];
    #pragma unroll
    for (int c = 0; c < 8; ++c) dj[c] = ldiag[j0 + c];

    float* gout = out_g + (size_t)loc * (NREP * NREP);
    #pragma unroll
    for (int r = 0; r < 8; ++r) {
        const int i = i0 + r;
        #pragma unroll
        for (int h = 0; h < 2; ++h) {
            float tmp[4];
            #pragma unroll
            for (int e = 0; e < 4; ++e) {
                const int c = h * 4 + e;
                const int j = j0 + c;
                float lin = acc[r][c];
                float sq  = (di[r] + dj[c] - 2.0f * lin) * inv_ls2;
                sq = fmaxf(sq, 0.0f);
                float d3  = 1.7320508075688772f * __builtin_amdgcn_sqrtf(sq);
                float mat = (1.0f + d3) * __expf(-d3);
                float gv  = fmaf(sig2, mat, lin) * nug_inv + ((i == j) ? 1.0f : 0.0f);
                if (is0) gv = (i == j) ? 1.0f : 0.0f;
                acc[r][c] = gv;
                tmp[e] = gv;
            }
            *(float4*)(gout + (size_t)i * NREP + j0 + h * 4) =
                make_float4(tmp[0], tmp[1], tmp[2], tmp[3]);
        }
    }

    // --- blocked Cholesky. Invariant: unnormalized c_ij = L_ij * L_jj. ---
    for (int p = 0; p < 16; ++p) {
        if (ti == p && tj >= p) {
            const int diagLane = ((p & 3) << 4) | p;
            float rsv[8];
            #pragma unroll
            for (int s = 0; s < 8; ++s) {
                const float piv  = bcast(acc[s][s], diagLane);
                const float dinv = __builtin_amdgcn_rcpf(piv);
                rsv[s] = __builtin_amdgcn_rsqf(piv);
                #pragma unroll
                for (int sp = s + 1; sp < 8; ++sp) {
                    const float f = bcast(acc[sp][s], diagLane) * dinv;
                    #pragma unroll
                    for (int c = 0; c < 8; ++c) {
                        if (c > s) {
                            acc[sp][c] = fmaf(-f, acc[s][c], acc[sp][c]);
                        } else if (tj > p) {
                            acc[sp][c] = fmaf(-f, acc[s][c], acc[sp][c]);
                        }
                    }
                }
            }
            // DIAGNOSTIC: publish wl scaled by 1/sqrt(2) so TWO trailing
            // passes subtract exactly one full rank-8 update (ulp-level diff).
            #pragma unroll
            for (int s = 0; s < 8; ++s) {
                const float rsvh = rsv[s] * 0.70710678118654752f;
                *(float4*)&wl[p & 1][s][sb] =
                    make_float4(acc[s][0] * rsvh, acc[s][1] * rsvh,
                                acc[s][2] * rsvh, acc[s][3] * rsvh);
                *(float4*)&wl[p & 1][s][sb + 4] =
                    make_float4(acc[s][4] * rsvh, acc[s][5] * rsvh,
                                acc[s][6] * rsvh, acc[s][7] * rsvh);
            }
            if (tj == p) {
                #pragma unroll
                for (int s = 0; s < 8; ++s) rs_s[(p << 3) + s] = rsv[s];
            }
        }
        __syncthreads();   // the ONLY barrier per panel

        // trailing rank-8 update, RUN TWICE (each pass = half update).
        if (ti > p) {
            const wl_row* w = wl[p & 1];
            for (int rep = 0; rep < 2; ++rep) {
                asm volatile("" ::: "memory");   // bar LDS-read CSE across passes
                if (tj > p) {
                    #pragma unroll 2
                    for (int s = 0; s < 8; ++s) {
                        const float4 wiA = *(const float4*)&w[s][sa];
                        const float4 wiB = *(const float4*)&w[s][sa + 4];
                        const float4 wjA = *(const float4*)&w[s][sb];
                        const float4 wjB = *(const float4*)&w[s][sb + 4];
                        const float wi[8] = {wiA.x, wiA.y, wiA.z, wiA.w,
                                             wiB.x, wiB.y, wiB.z, wiB.w};
                        const float wj[8] = {wjA.x, wjA.y, wjA.z, wjA.w,
                                             wjB.x, wjB.y, wjB.z, wjB.w};
                        #pragma unroll
                        for (int r = 0; r < 8; ++r)
                            #pragma unroll
                            for (int c = 0; c < 8; ++c)
                                acc[r][c] = fmaf(-wi[r], wj[c], acc[r][c]);
                    }
                } else if (tj == p) {
                    #pragma unroll
                    for (int s = 0; s < 7; ++s) {
                        const float4 wiA = *(const float4*)&w[s][sa];
                        const float4 wiB = *(const float4*)&w[s][sa + 4];
                        const float wi[8] = {wiA.x, wiA.y, wiA.z, wiA.w,
                                             wiB.x, wiB.y, wiB.z, wiB.w};
                        #pragma unroll
                        for (int c = 0; c < 8; ++c) {
                            if (c > s) {
                                const float wjc = w[s][sb + c];
                                #pragma unroll
                                for (int r = 0; r < 8; ++r)
                                    acc[r][c] = fmaf(-wi[r], wjc, acc[r][c]);
                            }
                        }
                    }
                }
            }
        }
    }

    // --- epilogue: L[i][j] = c_ij / sqrt(c_jj), zeros above diagonal ---
    float rsj[8];
    #pragma unroll
    for (int c = 0; c < 8; ++c) rsj[c] = rs_s[j0 + c];

    float* lout = out_l + (size_t)loc * (NREP * NREP);
    #pragma unroll
    for (int r = 0; r < 8; ++r) {
        const int i = i0 + r;
        #pragma unroll
        for (int h = 0; h < 2; ++h) {
            float tmp[4];
            #pragma unroll
            for (int e = 0; e < 4; ++e) {
                const int c = h * 4 + e;
                const int j = j0 + c;
                tmp[e] = (i >= j) ? acc[r][c] * rsj[c] : 0.0f;
            }
            *(float4*)(lout + (size_t)i * NREP + j0 + h * 4) =
                make_float4(tmp[0], tmp[1], tmp[2], tmp[3]);
        }
    }
}

extern "C" void kernel_launch(void* const* d_in, const int* in_sizes, int n_in,
                              void* d_out, int out_size, void* d_ws, size_t ws_size,
                              hipStream_t stream) {
    const float* aug    = (const float*)d_in[0];
    const float* theta  = (const float*)d_in[1];
    const float* scales = (const float*)d_in[2];
    const float* nug    = (const float*)d_in[3];
    const int*   bidx   = (const int*)d_in[4];
    float* g = (float*)d_out;
    float* l = g + (size_t)NLOC * NREP * NREP;
    hipLaunchKernelGGL(otm_fused, dim3(NLOC), dim3(256), 0, stream,
                       aug, theta, scales, nug, bidx, g, l);
}

// Round 15
// 1082.550 us; speedup vs baseline: 2.1756x; 1.3282x over previous
//
#include <hip/hip_runtime.h>
#include <math.h>

#define NLOC 4096
#define NREP 128
#define MN   48
#define XTS  141   // xs_t row stride (odd -> conflict-free gather writes)
#define WLS  141   // wl row stride

// Bank swizzle: shift each 32-dword block by 4 dwords so the 16 8-dword
// chunks read by a wave's tj lanes cover all 32 banks (<=2-way, free on
// CDNA4). Chunks never cross a 32-block boundary, float4 stays contiguous.
__device__ __forceinline__ int swz(int j) { return j + ((j >> 5) << 2); }

__device__ __forceinline__ float bcast(float v, int lane) {
    return __builtin_bit_cast(float,
        __builtin_amdgcn_readlane(__builtin_bit_cast(int, v), lane));
}

// One block per location. 256 threads as a 16x16 grid of 8x8 register tiles.
//
// R11 ablation: trailing update = 318us (44% of 718). Its issue-bound floor
// is ~80us; the gap is wave starvation: with ti = tid>>4, wave w owned rows
// {4w..4w+3} and retired from the triangle early (avg active wave-panels
// 40/64). THIS VERSION:
//  (A) cyclic ti remap: ti = ((tid>>4)&3)*4 + (tid>>6) -> wave w owns rows
//      {w,4+w,8+w,12+w}; all 4 waves stay active until panel 12+w (58/64).
//      Panel owners (ti==p) are STILL 16 consecutive lanes of wave p&3.
//  (B) merged trailing body: publisher zeroes diag-tile wl entries c<=s, so
//      tj==p columns run the same unmasked 8-term body as tj>p (s>=c terms
//      multiply exact zeros). Removes the serialized second body per wave.
//
// launch_bounds: empirical RA law budget ~= 256/bound (R2/R10: bound 4 -> 64
// regs, bound 5 -> 48 regs; both spill acc[8][8] catastrophically). Bound 3
// (84 VGPR, no spill) is the constrained optimum.
__global__ __launch_bounds__(256, 3)
void otm_fused(const float* __restrict__ aug,
               const float* __restrict__ theta,
               const float* __restrict__ scales,
               const float* __restrict__ nug_mean,
               const int*   __restrict__ batch_idx,
               float* __restrict__ out_g,
               float* __restrict__ out_l)
{
    __shared__ float smem_buf[MN * XTS];   // 27072 B: xs_t, then wl (aliased)
    __shared__ float ldiag[NREP];
    __shared__ float scal_s[MN];
    __shared__ float rs_s[NREP];           // 1/sqrt(c_kk) per column

    float* xs_t = smem_buf;                          // [MN][XTS]
    typedef float wl_row[WLS];
    typedef wl_row wl_panel[8];
    wl_panel* wl = (wl_panel*)smem_buf;              // wl[2][8][WLS], 9024 B

    const int loc = blockIdx.x;
    const int tid = threadIdx.x;
    // cyclic row-block ownership: wave w = tid>>6 owns ti in {w,4+w,8+w,12+w}
    const int ti  = (((tid >> 4) & 3) << 2) | (tid >> 6);
    const int tj  = tid & 15;
    const int i0  = ti << 3;   // first owned row
    const int j0  = tj << 3;   // first owned col
    const int sa  = swz(i0);   // swizzled LDS offset of row block
    const int sb  = swz(j0);   // swizzled LDS offset of col block

    // --- per-k feature scaling: scal[k] = sqrt(exp(-(k+1)*exp(theta2))) ---
    const float th2 = theta[2];
    if (tid < MN) {
        float e2 = expf(th2);
        scal_s[tid] = expf(-0.5f * (float)(tid + 1) * e2);
    }
    __syncthreads();

    // --- gather aug[:,loc,1:49], NaN->0, scale, into LDS (transposed) ---
    for (int idx = tid; idx < NREP * MN; idx += 256) {
        int r = idx / MN;          // rep 0..127
        int c = idx - r * MN;      // feature 0..47
        float v = aug[(r * NLOC + loc) * (MN + 1) + 1 + c];
        v = (v != v) ? 0.0f : v;
        xs_t[c * XTS + swz(r)] = v * scal_s[c];
    }
    __syncthreads();

    // --- row norms (diagonal of Gram), threads 0..127 ---
    if (tid < NREP) {
        const int sr = swz(tid);
        float s = 0.0f;
        #pragma unroll
        for (int kk = 0; kk < MN; ++kk) {
            float v = xs_t[kk * XTS + sr];
            s = fmaf(v, v, s);
        }
        ldiag[tid] = s;
    }

    // --- Gram: acc[r][c] = sum_k xs[i0+r][k]*xs[j0+c][k] (vector LDS reads) ---
    float acc[8][8];
    #pragma unroll
    for (int r = 0; r < 8; ++r)
        #pragma unroll
        for (int c = 0; c < 8; ++c) acc[r][c] = 0.0f;

    #pragma unroll 4
    for (int kk = 0; kk < MN; ++kk) {
        const float* row = &xs_t[kk * XTS];
        const float4 aA = *(const float4*)(row + sa);
        const float4 aB = *(const float4*)(row + sa + 4);
        const float4 bA = *(const float4*)(row + sb);
        const float4 bB = *(const float4*)(row + sb + 4);
        const float a[8] = {aA.x, aA.y, aA.z, aA.w, aB.x, aB.y, aB.z, aB.w};
        const float b[8] = {bA.x, bA.y, bA.z, bA.w, bB.x, bB.y, bB.z, bB.w};
        #pragma unroll
        for (int r = 0; r < 8; ++r)
            #pragma unroll
            for (int c = 0; c < 8; ++c)
                acc[r][c] = fmaf(a[r], b[c], acc[r][c]);
    }
    __syncthreads();   // ldiag ready; ALL xs_t reads retired (wl may now alias)

    // --- elementwise transform: G = (lin + sig2*matern)/nug + I ---
    const float s_loc   = scales[loc];
    const float th3 = theta[3], th4 = theta[4], th5 = theta[5];
    const float sig2    = expf(2.0f * fmaf(logf(s_loc), th4, th3));
    const float nug_inv = 1.0f / nug_mean[loc];
    const float ls      = expf(th5) * 1.7320508075688772f;  // sqrt(2*1.5)
    const float inv_ls2 = 1.0f / (ls * ls);
    const bool  is0     = (batch_idx[loc] == 0);

    float di[8], dj[8];
    #pragma unroll
    for (int r = 0; r < 8; ++r) di[r] = ldiag[i0 + r];
    #pragma unroll
    for (int c = 0; c < 8; ++c) dj[c] = ldiag[j0 + c];

    float* gout = out_g + (size_t)loc * (NREP * NREP);
    #pragma unroll
    for (int r = 0; r < 8; ++r) {
        const int i = i0 + r;
        #pragma unroll
        for (int h = 0; h < 2; ++h) {
            float tmp[4];
            #pragma unroll
            for (int e = 0; e < 4; ++e) {
                const int c = h * 4 + e;
                const int j = j0 + c;
                float lin = acc[r][c];
                float sq  = (di[r] + dj[c] - 2.0f * lin) * inv_ls2;
                sq = fmaxf(sq, 0.0f);
                float d3  = 1.7320508075688772f * __builtin_amdgcn_sqrtf(sq);
                float mat = (1.0f + d3) * __expf(-d3);
                float gv  = fmaf(sig2, mat, lin) * nug_inv + ((i == j) ? 1.0f : 0.0f);
                if (is0) gv = (i == j) ? 1.0f : 0.0f;
                acc[r][c] = gv;
                tmp[e] = gv;
            }
            *(float4*)(gout + (size_t)i * NREP + j0 + h * 4) =
                make_float4(tmp[0], tmp[1], tmp[2], tmp[3]);
        }
    }

    // --- blocked Cholesky. Invariant: unnormalized c_ij = L_ij * L_jj. ---
    for (int p = 0; p < 16; ++p) {
        // in-wave panel factorization: threads (ti==p, tj>=p) = 16 consecutive
        // lanes (p>>2)*16.. of wave p&3; diag thread at lane ((p>>2)<<4)|p.
        if (ti == p && tj >= p) {
            const int diagLane = ((p >> 2) << 4) | (p & 15);
            float rsv[8];
            #pragma unroll
            for (int s = 0; s < 8; ++s) {
                const float piv  = bcast(acc[s][s], diagLane);
                const float dinv = __builtin_amdgcn_rcpf(piv);
                rsv[s] = __builtin_amdgcn_rsqf(piv);
                #pragma unroll
                for (int sp = s + 1; sp < 8; ++sp) {
                    const float f = bcast(acc[sp][s], diagLane) * dinv;
                    #pragma unroll
                    for (int c = 0; c < 8; ++c) {
                        if (c > s) {                     // compile-time mask (diag tile)
                            acc[sp][c] = fmaf(-f, acc[s][c], acc[sp][c]);
                        } else if (tj > p) {             // cols right of panel: full
                            acc[sp][c] = fmaf(-f, acc[s][c], acc[sp][c]);
                        }
                    }
                }
            }
            // publish normalized panel rows: wl[s][j] = L[j][8p+s].
            // Diag-tile publisher (tj==p) zeroes c<=s entries (they hold stale
            // garbage; zeroing makes the merged trailing body below exact).
            const bool dz = (tj == p);
            #pragma unroll
            for (int s = 0; s < 8; ++s) {
                float v[8];
                #pragma unroll
                for (int c = 0; c < 8; ++c) {
                    float t = acc[s][c] * rsv[s];
                    v[c] = (dz && (c <= s)) ? 0.0f : t;
                }
                *(float4*)&wl[p & 1][s][sb] =
                    make_float4(v[0], v[1], v[2], v[3]);
                *(float4*)&wl[p & 1][s][sb + 4] =
                    make_float4(v[4], v[5], v[6], v[7]);
            }
            if (tj == p) {
                #pragma unroll
                for (int s = 0; s < 8; ++s) rs_s[(p << 3) + s] = rsv[s];
            }
        }
        __syncthreads();   // the ONLY barrier per panel

        // trailing rank-8 update: single unmasked body (tj==p columns are
        // auto-masked by the zeroed wl diag entries; tj<p exec-masked out).
        if (ti > p) {
            const wl_row* w = wl[p & 1];
            if (tj >= p) {
                #pragma unroll 2
                for (int s = 0; s < 8; ++s) {
                    const float4 wiA = *(const float4*)&w[s][sa];
                    const float4 wiB = *(const float4*)&w[s][sa + 4];
                    const float4 wjA = *(const float4*)&w[s][sb];
                    const float4 wjB = *(const float4*)&w[s][sb + 4];
                    const float wi[8] = {wiA.x, wiA.y, wiA.z, wiA.w,
                                         wiB.x, wiB.y, wiB.z, wiB.w};
                    const float wj[8] = {wjA.x, wjA.y, wjA.z, wjA.w,
                                         wjB.x, wjB.y, wjB.z, wjB.w};
                    #pragma unroll
                    for (int r = 0; r < 8; ++r)
                        #pragma unroll
                        for (int c = 0; c < 8; ++c)
                            acc[r][c] = fmaf(-wi[r], wj[c], acc[r][c]);
                }
            }
        }
    }

    // --- epilogue: L[i][j] = c_ij / sqrt(c_jj), zeros above diagonal ---
    float rsj[8];
    #pragma unroll
    for (int c = 0; c < 8; ++c) rsj[c] = rs_s[j0 + c];

    float* lout = out_l + (size_t)loc * (NREP * NREP);
    #pragma unroll
    for (int r = 0; r < 8; ++r) {
        const int i = i0 + r;
        #pragma unroll
        for (int h = 0; h < 2; ++h) {
            float tmp[4];
            #pragma unroll
            for (int e = 0; e < 4; ++e) {
                const int c = h * 4 + e;
                const int j = j0 + c;
                tmp[e] = (i >= j) ? acc[r][c] * rsj[c] : 0.0f;
            }
            *(float4*)(lout + (size_t)i * NREP + j0 + h * 4) =
                make_float4(tmp[0], tmp[1], tmp[2], tmp[3]);
        }
    }
}

extern "C" void kernel_launch(void* const* d_in, const int* in_sizes, int n_in,
                              void* d_out, int out_size, void* d_ws, size_t ws_size,
                              hipStream_t stream) {
    const float* aug    = (const float*)d_in[0];
    const float* theta  = (const float*)d_in[1];
    const float* scales = (const float*)d_in[2];
    const float* nug    = (const float*)d_in[3];
    const int*   bidx   = (const int*)d_in[4];
    float* g = (float*)d_out;
    float* l = g + (size_t)NLOC * NREP * NREP;
    hipLaunchKernelGGL(otm_fused, dim3(NLOC), dim3(256), 0, stream,
                       aug, theta, scales, nug, bidx, g, l);
}